// Round 12
// baseline (57.007 us; speedup 1.0000x reference)
//
#include <hip/hip_runtime.h>

// SSIM via MFMA: both separable 11-tap Gaussian passes are matmuls by a
// constant banded matrix (f16 inputs, f32 accumulate). V-pass computed
// transposed so each lane's V output IS the H-pass A-fragment (R7/R8
// verified). f16-weight-sum scale corrected by 1/t (R8).
// R12: staging via __builtin_amdgcn_global_load_lds (async DMA, no VGPR
// round-trip). R10/R11 proved the compiler sinks register-staged loads
// (VGPR stuck at 48, dur flat 50us); gload_lds queues all 148 row-loads
// on vmcnt and drains ONCE at the barrier. Patch stored as raw f32
// row-major [2][80][84] (53.8 KB, 3 blocks/CU); f32->f16 cvt moves to the
// V-pass LDS read (stride 84 -> 2 lanes/bank, conflict-free). Rows 74-79
// zeroed (dead k-slots must read finite data). Edge blocks: zero-fill +
// masked loads.

typedef _Float16 f16;
typedef __attribute__((ext_vector_type(4))) _Float16 f16x4;
typedef __attribute__((ext_vector_type(8))) _Float16 f16x8;
typedef __attribute__((ext_vector_type(4))) float f32x4;

#define IMGW 512
#define IMGH 512
#define NPL 48           // 16*3 planes
#define NBLOCKS (NPL * 8 * 8)   // 3072: 64x64 tile per block
#define NPIX 12582912.0
#define REDT 1024

#define SRW 84                  // dword stride per patch row (16B-aligned, bank-safe)
#define PROWS 80                // 74 loaded rows + 6 zeroed (dead-slot reads)
#define IMGOFFD (PROWS * SRW)   // 6720 dwords per image

// inverse of total f16-weight scale: s = sum of f16(G) = 1048748/2^20, t = s^2
#define INV_T 0.99967202f

// 11-tap gaussian, sigma=1.5, normalized (double-precision precomputed)
__device__ const float G_dev[11] = {0.00102838f, 0.00759876f, 0.03600077f,
                                    0.10936069f, 0.21300554f, 0.26601172f,
                                    0.21300554f, 0.10936069f, 0.03600077f,
                                    0.00759876f, 0.00102838f};

__global__ __launch_bounds__(256, 3) void ssim_main(const float* __restrict__ img1,
                                                    const float* __restrict__ img2,
                                                    float* __restrict__ partial) {
    __shared__ __align__(16) float sP[2 * IMGOFFD];   // 53760 B
    __shared__ float wsum[4];

    const int tid  = threadIdx.x;
    const int lane = tid & 63;
    const int wv   = tid >> 6;         // wave 0..3 (stacked vertically)
    const int l15  = lane & 15;
    const int lg   = lane >> 4;        // 0..3

    const int bid   = blockIdx.x;
    const int plane = bid >> 6;        // 64 tiles per plane
    const int rem   = bid & 63;
    const int by    = rem >> 3;
    const int bx    = rem & 7;
    const int R0    = by * 64 - 5;          // patch row 0 -> image row
    const int AC0   = bx * 64 - 8;          // patch col 0 -> image col (x4B=16B aligned)

    const float* __restrict__ p1 = img1 + (size_t)plane * (IMGH * IMGW);
    const float* __restrict__ p2 = img2 + (size_t)plane * (IMGH * IMGW);

    // ---------- staging bounds (uniform per block) ----------
    const int rlo = (R0 < 0) ? -R0 : 0;                   // first valid patch row
    const int rhi = (R0 + 74 > IMGH) ? (IMGH - R0) : 74;  // one past last valid
    const int llo = (AC0 < 0) ? ((-AC0 + 3) >> 2) : 0;    // first active lane
    const int lhic = (IMGW - AC0) >> 2;
    const int lhi = (lhic < 20) ? lhic : 20;              // one past last active lane
    const bool edge = (rlo != 0) | (rhi != 74) | (llo != 0) | (lhi != 20);

    if (edge) {
        // zero the whole patch (both images): 6720 float2
        for (int it = 0; it < 27; ++it) {
            const int i = tid + it * 256;
            if (i < 6720) *(float2*)&sP[2 * i] = make_float2(0.0f, 0.0f);
        }
        __syncthreads();     // zeros visible before DMA writes land
    } else {
        // zero rows 74..79 of both images: 504 float2 (disjoint from loads)
        #pragma unroll
        for (int it = 0; it < 2; ++it) {
            const int i = tid + it * 256;
            if (i < 504) {
                const int im = (i >= 252) ? 1 : 0;
                const int k  = i - im * 252;
                *(float2*)&sP[im * IMGOFFD + 74 * SRW + 2 * k] = make_float2(0.0f, 0.0f);
            }
        }
    }

    // ---------- async staging: one global_load_lds (width 16) per row ----------
    // lane i covers patch cols 4i..4i+3; LDS dest = uniform row base + lane*16.
    {
        const int nr = rhi - rlo;
        for (int L = wv; L < 2 * nr; L += 4) {
            const int im  = (L >= nr) ? 1 : 0;
            const int row = rlo + (L - im * nr);
            const float* __restrict__ bp = im ? p2 : p1;
            float* lp = &sP[im * IMGOFFD + row * SRW];    // wave-uniform base
            if (lane >= llo && lane < lhi) {
                const float* gp = bp + (size_t)(R0 + row) * IMGW + (AC0 + 4 * lane);
                __builtin_amdgcn_global_load_lds(gp, lp, 16, 0, 0);
            }
        }
    }
    __syncthreads();   // drains vmcnt (DMA) + lgkmcnt (zero writes) once

    // ---------- constant band fragment: B[k][n] = G[kap(k) - n], n = l15 ----------
    // kap[j] = 4lg+j (j<4), 16+4lg+(j-4) (j>=4)
    f16x8 bband;
    #pragma unroll
    for (int j = 0; j < 8; ++j) {
        const int kj = (j < 4) ? (4 * lg + j) : (16 + 4 * lg + (j - 4));
        const int t  = kj - l15;
        const float w = (t >= 0 && t < 11) ? G_dev[t] : 0.0f;
        bband[j] = (f16)w;
    }

    const f32x4 zero4 = {0.0f, 0.0f, 0.0f, 0.0f};

    // ---------- V-pass: A[i=vcol][k=row-slot] from LDS (f32->f16), mfma ----------
    f16x4 hv[5][5];    // [chunk][quantity: x,y,xx,yy,xy]
    #pragma unroll
    for (int t = 0; t < 5; ++t) {
        int p = 3 + 16 * t + l15;
        if (t == 4) p = (p > PROWS - 1) ? PROWS - 1 : p;   // dead vcols, clamp
        const int ro = 16 * wv + 4 * lg;
        const float* __restrict__ b1 = &sP[ro * SRW + p];
        const float* __restrict__ b2 = &sP[IMGOFFD + ro * SRW + p];
        f16x8 fx, fy;
        #pragma unroll
        for (int e = 0; e < 4; ++e) {
            fx[e]     = (f16)b1[e * SRW];
            fx[e + 4] = (f16)b1[(16 + e) * SRW];
            fy[e]     = (f16)b2[e * SRW];
            fy[e + 4] = (f16)b2[(16 + e) * SRW];
        }
        const f16x8 fxx = fx * fx;   // v_pk_mul_f16
        const f16x8 fyy = fy * fy;
        const f16x8 fxy = fx * fy;

        const f32x4 dx  = __builtin_amdgcn_mfma_f32_16x16x32_f16(fx,  bband, zero4, 0, 0, 0);
        const f32x4 dy  = __builtin_amdgcn_mfma_f32_16x16x32_f16(fy,  bband, zero4, 0, 0, 0);
        const f32x4 dxx = __builtin_amdgcn_mfma_f32_16x16x32_f16(fxx, bband, zero4, 0, 0, 0);
        const f32x4 dyy = __builtin_amdgcn_mfma_f32_16x16x32_f16(fyy, bband, zero4, 0, 0, 0);
        const f32x4 dxy = __builtin_amdgcn_mfma_f32_16x16x32_f16(fxy, bband, zero4, 0, 0, 0);

        hv[t][0] = (f16x4){(f16)dx[0],  (f16)dx[1],  (f16)dx[2],  (f16)dx[3]};
        hv[t][1] = (f16x4){(f16)dy[0],  (f16)dy[1],  (f16)dy[2],  (f16)dy[3]};
        hv[t][2] = (f16x4){(f16)dxx[0], (f16)dxx[1], (f16)dxx[2], (f16)dxx[3]};
        hv[t][3] = (f16x4){(f16)dyy[0], (f16)dyy[1], (f16)dyy[2], (f16)dyy[3]};
        hv[t][4] = (f16x4){(f16)dxy[0], (f16)dxy[1], (f16)dxy[2], (f16)dxy[3]};
    }

    // ---------- H-pass + ssim ----------
    float acc = 0.0f;
    const float C1 = 1.0e-4f;   // 0.01^2
    const float C2 = 9.0e-4f;   // 0.03^2
    #pragma unroll
    for (int m = 0; m < 4; ++m) {
        f32x4 h[5];
        #pragma unroll
        for (int q = 0; q < 5; ++q) {
            const f16x8 a = __builtin_shufflevector(hv[m][q], hv[m + 1][q],
                                                    0, 1, 2, 3, 4, 5, 6, 7);
            h[q] = __builtin_amdgcn_mfma_f32_16x16x32_f16(a, bband, zero4, 0, 0, 0);
            h[q] *= INV_T;   // remove f16-weight-sum scale (s^2 per quantity)
        }
        #pragma unroll
        for (int r = 0; r < 4; ++r) {
            const float mu1 = h[0][r], mu2 = h[1][r];
            const float exx = h[2][r], eyy = h[3][r], exy = h[4][r];
            const float mu1s = mu1 * mu1;
            const float mu2s = mu2 * mu2;
            const float mu12 = mu1 * mu2;
            const float s1  = exx - mu1s;
            const float s2  = eyy - mu2s;
            const float s12 = exy - mu12;
            const float num = fmaf(2.0f, mu12, C1) * fmaf(2.0f, s12, C2);
            const float den = (mu1s + mu2s + C1) * (s1 + s2 + C2);
            float rd = __builtin_amdgcn_rcpf(den);   // den > 0 always
            rd = rd * fmaf(-den, rd, 2.0f);          // Newton step
            acc = fmaf(num, rd, acc);
        }
    }

    // ---------- block reduction ----------
    #pragma unroll
    for (int off = 32; off > 0; off >>= 1)
        acc += __shfl_down(acc, off, 64);
    if (lane == 0) wsum[wv] = acc;
    __syncthreads();
    if (tid == 0)
        partial[bid] = (wsum[0] + wsum[1]) + (wsum[2] + wsum[3]);
}

__global__ __launch_bounds__(REDT) void ssim_reduce(const float* __restrict__ partial,
                                                    float* __restrict__ out) {
    const int tid = threadIdx.x;
    double s = 0.0;
    for (int i = tid; i < NBLOCKS; i += REDT)
        s += (double)partial[i];
    #pragma unroll
    for (int off = 32; off > 0; off >>= 1)
        s += __shfl_down(s, off, 64);
    __shared__ double wsd[REDT / 64];
    if ((tid & 63) == 0) wsd[tid >> 6] = s;
    __syncthreads();
    if (tid == 0) {
        double t = 0.0;
        #pragma unroll
        for (int i = 0; i < REDT / 64; ++i) t += wsd[i];
        out[0] = (float)(t / NPIX);
    }
}

extern "C" void kernel_launch(void* const* d_in, const int* in_sizes, int n_in,
                              void* d_out, int out_size, void* d_ws, size_t ws_size,
                              hipStream_t stream) {
    const float* img1 = (const float*)d_in[0];
    const float* img2 = (const float*)d_in[1];
    float* partial = (float*)d_ws;      // 3072 floats
    float* out = (float*)d_out;
    ssim_main<<<NBLOCKS, 256, 0, stream>>>(img1, img2, partial);
    ssim_reduce<<<1, REDT, 0, stream>>>(partial, out);
}

// Round 13
// 52.161 us; speedup vs baseline: 1.0929x; 1.0929x over previous
//
#include <hip/hip_runtime.h>

// SSIM via MFMA, R13: H-pass-FIRST from row-major f32 LDS.
// Staging: __builtin_amdgcn_global_load_lds (async DMA, single vmcnt drain,
// kept from R12 — it removed the 13 serial HBM exposures of R9/R11).
// Compute: H-pass A-fragment k-slots are COLUMNS -> row-major LDS gives each
// lane its 8 k-slots as 2x ds_read_b128 (aligned, stride-84 rows = 2-way bank
// alias = free). H output D(row=4lg+reg, col=l15) IS the V-pass A-fragment
// (i=col=l15, k-slots = stripe0/stripe1 regs) -> H->V handoff is pure
// in-register f32->f16 cvt, no LDS, no shuffles. Two band fragments: H band
// G[k-n-3] (patch col0 = c0-8, halo offset), V band G[k-n]. Dead k-slots
// (>=26) have B=0; their A reads are row-clamped to 73 (finite). LDS 49.7 KB
// (74 rows, no zero-rows) -> 3 blocks/CU. f16-weight-sum scale 1/t (R8).

typedef _Float16 f16;
typedef __attribute__((ext_vector_type(8))) _Float16 f16x8;
typedef __attribute__((ext_vector_type(4))) float f32x4;

#define IMGW 512
#define IMGH 512
#define NPL 48           // 16*3 planes
#define NBLOCKS (NPL * 8 * 8)   // 3072: 64x64 tile per block
#define NPIX 12582912.0
#define REDT 1024

#define SRW 84                  // dword stride per patch row (16B-aligned)
#define PR 74                   // patch rows
#define IMGOFFD (PR * SRW)      // 6216 dwords per image

// inverse of total f16-weight scale: s = sum of f16(G) = 1048748/2^20, t = s^2
#define INV_T 0.99967202f

// 11-tap gaussian, sigma=1.5, normalized (double-precision precomputed)
__device__ const float G_dev[11] = {0.00102838f, 0.00759876f, 0.03600077f,
                                    0.10936069f, 0.21300554f, 0.26601172f,
                                    0.21300554f, 0.10936069f, 0.03600077f,
                                    0.00759876f, 0.00102838f};

__global__ __launch_bounds__(256, 3) void ssim_main(const float* __restrict__ img1,
                                                    const float* __restrict__ img2,
                                                    float* __restrict__ partial) {
    __shared__ __align__(16) float sP[2 * IMGOFFD];   // 49728 B
    __shared__ float wsum[4];

    const int tid  = threadIdx.x;
    const int lane = tid & 63;
    const int wv   = tid >> 6;         // wave 0..3 (stacked vertically)
    const int l15  = lane & 15;
    const int lg   = lane >> 4;        // 0..3

    const int bid   = blockIdx.x;
    const int plane = bid >> 6;        // 64 tiles per plane
    const int rem   = bid & 63;
    const int by    = rem >> 3;
    const int bx    = rem & 7;
    const int R0    = by * 64 - 5;          // patch row 0 -> image row
    const int AC0   = bx * 64 - 8;          // patch col 0 -> image col (16B aligned)

    const float* __restrict__ p1 = img1 + (size_t)plane * (IMGH * IMGW);
    const float* __restrict__ p2 = img2 + (size_t)plane * (IMGH * IMGW);

    const bool interior = (by >= 1) & (by <= 6) & (bx >= 1) & (bx <= 6);

    // ---------- staging: async DMA, one width-16 gload_lds per row ----------
    if (interior) {
        for (int r = wv; r < PR; r += 4) {
            if (lane < 21) {
                const float* gp = p1 + (size_t)(R0 + r) * IMGW + (AC0 + 4 * lane);
                __builtin_amdgcn_global_load_lds(gp, &sP[r * SRW], 16, 0, 0);
            }
        }
        for (int r = wv; r < PR; r += 4) {
            if (lane < 21) {
                const float* gp = p2 + (size_t)(R0 + r) * IMGW + (AC0 + 4 * lane);
                __builtin_amdgcn_global_load_lds(gp, &sP[IMGOFFD + r * SRW], 16, 0, 0);
            }
        }
    } else {
        // zero whole patch (conv zero-padding), then masked DMA of valid region
        for (int it = 0; it < 25; ++it) {
            const int i = tid + it * 256;
            if (i < IMGOFFD) ((float2*)sP)[i] = make_float2(0.0f, 0.0f);
        }
        __syncthreads();     // zeros visible before DMA writes land
        const int rlo = (R0 < 0) ? -R0 : 0;
        const int rhi = (R0 + PR > IMGH) ? (IMGH - R0) : PR;
        const int llo = (AC0 < 0) ? ((-AC0) >> 2) : 0;
        const int lhiT = (IMGW - AC0) >> 2;
        const int lhi = (lhiT < 21) ? lhiT : 21;
        for (int r = rlo + wv; r < rhi; r += 4) {
            if (lane >= llo && lane < lhi) {
                const float* gp = p1 + (size_t)(R0 + r) * IMGW + (AC0 + 4 * lane);
                __builtin_amdgcn_global_load_lds(gp, &sP[r * SRW], 16, 0, 0);
            }
        }
        for (int r = rlo + wv; r < rhi; r += 4) {
            if (lane >= llo && lane < lhi) {
                const float* gp = p2 + (size_t)(R0 + r) * IMGW + (AC0 + 4 * lane);
                __builtin_amdgcn_global_load_lds(gp, &sP[IMGOFFD + r * SRW], 16, 0, 0);
            }
        }
    }
    __syncthreads();   // single drain of the whole DMA queue

    // ---------- band fragments: B[k][n], k = kap(lg,j), n = l15 ----------
    // kap[j] = 4lg+j (j<4), 16+4lg+(j-4) (j>=4)
    f16x8 bbH, bbV;
    #pragma unroll
    for (int j = 0; j < 8; ++j) {
        const int kj = (j < 4) ? (4 * lg + j) : (16 + 4 * lg + (j - 4));
        const int tH = kj - l15 - 3;    // H: patch col halo offset 3
        const int tV = kj - l15;        // V: window row 0 = outrow - 5
        bbH[j] = (f16)((tH >= 0 && tH < 11) ? G_dev[tH] : 0.0f);
        bbV[j] = (f16)((tV >= 0 && tV < 11) ? G_dev[tV] : 0.0f);
    }

    const f32x4 zero4 = {0.0f, 0.0f, 0.0f, 0.0f};

    // H-pass A-read rows (lane = stripe row i = l15); stripe1 clamped (dead
    // k-slots >=26 have bbV=0, just need finite data).
    const int rowA = 16 * wv + l15;
    int rowB = 16 * wv + 16 + l15;
    if (rowB > PR - 1) rowB = PR - 1;

    float acc = 0.0f;
    const float C1 = 1.0e-4f;   // 0.01^2
    const float C2 = 9.0e-4f;   // 0.03^2

    #pragma unroll
    for (int m = 0; m < 4; ++m) {
        const int cg = 16 * m + 4 * lg;    // k-slot col group (16B aligned)
        f32x4 D0[5], D1[5];
        #pragma unroll
        for (int s = 0; s < 2; ++s) {
            const int row = s ? rowB : rowA;
            const float* __restrict__ r1 = &sP[row * SRW];
            const float* __restrict__ r2 = &sP[IMGOFFD + row * SRW];
            const f32x4 xa = *(const f32x4*)&r1[cg];
            const f32x4 xb = *(const f32x4*)&r1[cg + 16];
            const f32x4 ya = *(const f32x4*)&r2[cg];
            const f32x4 yb = *(const f32x4*)&r2[cg + 16];
            f16x8 fx, fy;
            #pragma unroll
            for (int e = 0; e < 4; ++e) {
                fx[e]     = (f16)xa[e];
                fx[e + 4] = (f16)xb[e];
                fy[e]     = (f16)ya[e];
                fy[e + 4] = (f16)yb[e];
            }
            const f16x8 fxx = fx * fx;   // v_pk_mul_f16
            const f16x8 fyy = fy * fy;
            const f16x8 fxy = fx * fy;
            f32x4* D = s ? D1 : D0;
            D[0] = __builtin_amdgcn_mfma_f32_16x16x32_f16(fx,  bbH, zero4, 0, 0, 0);
            D[1] = __builtin_amdgcn_mfma_f32_16x16x32_f16(fy,  bbH, zero4, 0, 0, 0);
            D[2] = __builtin_amdgcn_mfma_f32_16x16x32_f16(fxx, bbH, zero4, 0, 0, 0);
            D[3] = __builtin_amdgcn_mfma_f32_16x16x32_f16(fyy, bbH, zero4, 0, 0, 0);
            D[4] = __builtin_amdgcn_mfma_f32_16x16x32_f16(fxy, bbH, zero4, 0, 0, 0);
        }
        // V-pass: lane's H outputs (rows 4lg+reg, col l15) ARE its A-fragment
        f32x4 h[5];
        #pragma unroll
        for (int q = 0; q < 5; ++q) {
            f16x8 av;
            #pragma unroll
            for (int j = 0; j < 4; ++j) {
                av[j]     = (f16)D0[q][j];
                av[j + 4] = (f16)D1[q][j];
            }
            h[q] = __builtin_amdgcn_mfma_f32_16x16x32_f16(av, bbV, zero4, 0, 0, 0);
            h[q] *= INV_T;   // remove f16-weight-sum scale (s^2 per quantity)
        }
        #pragma unroll
        for (int r = 0; r < 4; ++r) {
            const float mu1 = h[0][r], mu2 = h[1][r];
            const float exx = h[2][r], eyy = h[3][r], exy = h[4][r];
            const float mu1s = mu1 * mu1;
            const float mu2s = mu2 * mu2;
            const float mu12 = mu1 * mu2;
            const float s1  = exx - mu1s;
            const float s2  = eyy - mu2s;
            const float s12 = exy - mu12;
            const float num = fmaf(2.0f, mu12, C1) * fmaf(2.0f, s12, C2);
            const float den = (mu1s + mu2s + C1) * (s1 + s2 + C2);
            float rd = __builtin_amdgcn_rcpf(den);   // den > 0 always
            rd = rd * fmaf(-den, rd, 2.0f);          // Newton step
            acc = fmaf(num, rd, acc);
        }
    }

    // ---------- block reduction ----------
    #pragma unroll
    for (int off = 32; off > 0; off >>= 1)
        acc += __shfl_down(acc, off, 64);
    if (lane == 0) wsum[wv] = acc;
    __syncthreads();
    if (tid == 0)
        partial[bid] = (wsum[0] + wsum[1]) + (wsum[2] + wsum[3]);
}

__global__ __launch_bounds__(REDT) void ssim_reduce(const float* __restrict__ partial,
                                                    float* __restrict__ out) {
    const int tid = threadIdx.x;
    double s = 0.0;
    for (int i = tid; i < NBLOCKS; i += REDT)
        s += (double)partial[i];
    #pragma unroll
    for (int off = 32; off > 0; off >>= 1)
        s += __shfl_down(s, off, 64);
    __shared__ double wsd[REDT / 64];
    if ((tid & 63) == 0) wsd[tid >> 6] = s;
    __syncthreads();
    if (tid == 0) {
        double t = 0.0;
        #pragma unroll
        for (int i = 0; i < REDT / 64; ++i) t += wsd[i];
        out[0] = (float)(t / NPIX);
    }
}

extern "C" void kernel_launch(void* const* d_in, const int* in_sizes, int n_in,
                              void* d_out, int out_size, void* d_ws, size_t ws_size,
                              hipStream_t stream) {
    const float* img1 = (const float*)d_in[0];
    const float* img2 = (const float*)d_in[1];
    float* partial = (float*)d_ws;      // 3072 floats
    float* out = (float*)d_out;
    ssim_main<<<NBLOCKS, 256, 0, stream>>>(img1, img2, partial);
    ssim_reduce<<<1, REDT, 0, stream>>>(partial, out);
}